// Round 1
// baseline (180.674 us; speedup 1.0000x reference)
//
#include <hip/hip_runtime.h>

#define DT_C 0.01f

__global__ __launch_bounds__(256) void eskf_kernel(
    const float* __restrict__ x,      // (14, B)
    const float* __restrict__ state,  // (B, 7)
    const float* __restrict__ cov,    // (B, 36)
    const float* __restrict__ Qm,     // (B, 36)
    const float* __restrict__ Rm,     // (B, 49)
    float* __restrict__ out,          // (B, 7)
    int B)
{
    int b = blockIdx.x * blockDim.x + threadIdx.x;
    if (b >= B) return;

    // ---- loads (coalesced across lanes) ----
    float meas[7];
#pragma unroll
    for (int i = 0; i < 7; ++i) meas[i] = x[i * B + b];
    float tw[6];
#pragma unroll
    for (int i = 0; i < 6; ++i) tw[i] = x[(8 + i) * B + b];
    float st[7];
#pragma unroll
    for (int i = 0; i < 7; ++i) st[i] = state[b * 7 + i];

    // P = covariance + Q  (6x6), float4-vectorized (144B per batch, 16B aligned)
    float P[36];
    {
        const float4* c4 = (const float4*)(cov + (size_t)b * 36);
        const float4* q4 = (const float4*)(Qm  + (size_t)b * 36);
#pragma unroll
        for (int i = 0; i < 9; ++i) {
            float4 a = c4[i], bb = q4[i];
            P[4*i+0] = a.x + bb.x;
            P[4*i+1] = a.y + bb.y;
            P[4*i+2] = a.z + bb.z;
            P[4*i+3] = a.w + bb.w;
        }
    }

    // S starts as R (7x7)
    float S[7][7];
    {
        const float* r = Rm + (size_t)b * 49;
#pragma unroll
        for (int i = 0; i < 7; ++i)
#pragma unroll
            for (int j = 0; j < 7; ++j)
                S[i][j] = r[i * 7 + j];
    }

    // ---- predict_state = inject(state, DT*twist) ----
    float ps[7];
    {
        float d0 = 0.5f * DT_C * tw[3], d1 = 0.5f * DT_C * tw[4], d2 = 0.5f * DT_C * tw[5];
        ps[0] = st[0] + DT_C * tw[0];
        ps[1] = st[1] + DT_C * tw[1];
        ps[2] = st[2] + DT_C * tw[2];
        float w = st[3], xx = st[4], yy = st[5], zz = st[6];
        float qw = w - xx * d0 - yy * d1 - zz * d2;
        float qx = w * d0 + xx + yy * d2 - zz * d1;
        float qy = w * d1 - xx * d2 + yy + zz * d0;
        float qz = w * d2 + xx * d1 - yy * d0 + zz;
        float inv = rsqrtf(qw * qw + qx * qx + qy * qy + qz * qz);
        ps[3] = qw * inv; ps[4] = qx * inv; ps[5] = qy * inv; ps[6] = qz * inv;
    }

    // ---- H = [[I3,0],[0,Qd]] with Qd from ORIGINAL state quat ----
    float Qd[4][3];
    {
        float w = st[3], xx = st[4], yy = st[5], zz = st[6];
        Qd[0][0] = -0.5f * xx; Qd[0][1] = -0.5f * yy; Qd[0][2] = -0.5f * zz;
        Qd[1][0] =  0.5f * w;  Qd[1][1] = -0.5f * zz; Qd[1][2] =  0.5f * yy;
        Qd[2][0] =  0.5f * zz; Qd[2][1] =  0.5f * w;  Qd[2][2] = -0.5f * xx;
        Qd[3][0] = -0.5f * yy; Qd[3][1] =  0.5f * xx; Qd[3][2] =  0.5f * w;
    }

    // ---- S = H P H^T + R, exploiting block structure ----
    // S00 (3x3) += P00
#pragma unroll
    for (int i = 0; i < 3; ++i)
#pragma unroll
        for (int j = 0; j < 3; ++j)
            S[i][j] += P[i * 6 + j];

    // T (4x6) = Qd @ P[3:6, :]
    float T[4][6];
#pragma unroll
    for (int i = 0; i < 4; ++i)
#pragma unroll
        for (int c = 0; c < 6; ++c) {
            float acc = 0.f;
#pragma unroll
            for (int k = 0; k < 3; ++k) acc += Qd[i][k] * P[(3 + k) * 6 + c];
            T[i][c] = acc;
        }

    // S10 (4x3) += T[:, 0:3]
#pragma unroll
    for (int i = 0; i < 4; ++i)
#pragma unroll
        for (int j = 0; j < 3; ++j) S[3 + i][j] += T[i][j];

    // S01 (3x4) += P01 @ Qd^T
#pragma unroll
    for (int i = 0; i < 3; ++i)
#pragma unroll
        for (int j = 0; j < 4; ++j) {
            float acc = 0.f;
#pragma unroll
            for (int k = 0; k < 3; ++k) acc += P[i * 6 + 3 + k] * Qd[j][k];
            S[i][3 + j] += acc;
        }

    // S11 (4x4) += T[:, 3:6] @ Qd^T
#pragma unroll
    for (int i = 0; i < 4; ++i)
#pragma unroll
        for (int j = 0; j < 4; ++j) {
            float acc = 0.f;
#pragma unroll
            for (int l = 0; l < 3; ++l) acc += T[i][3 + l] * Qd[j][l];
            S[3 + i][3 + j] += acc;
        }

    // ---- innovation ----
    float y[7];
#pragma unroll
    for (int i = 0; i < 7; ++i) y[i] = meas[i] - ps[i];

    // ---- solve S y = innovation (no-pivot LU, S is SPD; fully unrolled) ----
#pragma unroll
    for (int k = 0; k < 7; ++k) {
        float inv = 1.0f / S[k][k];
#pragma unroll
        for (int i = k + 1; i < 7; ++i) {
            float f = S[i][k] * inv;
#pragma unroll
            for (int j = k + 1; j < 7; ++j) S[i][j] -= f * S[k][j];
            y[i] -= f * y[k];
        }
    }
#pragma unroll
    for (int k = 6; k >= 0; --k) {
        float acc = y[k];
#pragma unroll
        for (int j = k + 1; j < 7; ++j) acc -= S[k][j] * y[j];
        y[k] = acc / S[k][k];
    }

    // ---- error_state = P @ (H^T y) ----
    float z6[6];
    z6[0] = y[0]; z6[1] = y[1]; z6[2] = y[2];
#pragma unroll
    for (int c = 0; c < 3; ++c) {
        float acc = 0.f;
#pragma unroll
        for (int i = 0; i < 4; ++i) acc += Qd[i][c] * y[3 + i];
        z6[3 + c] = acc;
    }
    float es[6];
#pragma unroll
    for (int i = 0; i < 6; ++i) {
        float acc = 0.f;
#pragma unroll
        for (int j = 0; j < 6; ++j) acc += P[i * 6 + j] * z6[j];
        es[i] = acc;
    }

    // ---- new_state = inject(predict_state, error_state) ----
    float o0 = ps[0] + es[0];
    float o1 = ps[1] + es[1];
    float o2 = ps[2] + es[2];
    float d0 = 0.5f * es[3], d1 = 0.5f * es[4], d2 = 0.5f * es[5];
    float w = ps[3], xx = ps[4], yy = ps[5], zz = ps[6];
    float qw = w - xx * d0 - yy * d1 - zz * d2;
    float qx = w * d0 + xx + yy * d2 - zz * d1;
    float qy = w * d1 - xx * d2 + yy + zz * d0;
    float qz = w * d2 + xx * d1 - yy * d0 + zz;
    float inv = rsqrtf(qw * qw + qx * qx + qy * qy + qz * qz);

    float* o = out + (size_t)b * 7;
    o[0] = o0; o[1] = o1; o[2] = o2;
    o[3] = qw * inv; o[4] = qx * inv; o[5] = qy * inv; o[6] = qz * inv;
}

extern "C" void kernel_launch(void* const* d_in, const int* in_sizes, int n_in,
                              void* d_out, int out_size, void* d_ws, size_t ws_size,
                              hipStream_t stream) {
    const float* x     = (const float*)d_in[0];
    const float* state = (const float*)d_in[1];
    const float* cov   = (const float*)d_in[2];
    const float* Qm    = (const float*)d_in[3];
    const float* Rm    = (const float*)d_in[4];
    float* out = (float*)d_out;
    int B = in_sizes[1] / 7;
    int block = 256;
    int grid = (B + block - 1) / block;
    eskf_kernel<<<grid, block, 0, stream>>>(x, state, cov, Qm, Rm, out, B);
}

// Round 2
// 168.562 us; speedup vs baseline: 1.0719x; 1.0719x over previous
//
#include <hip/hip_runtime.h>

#define DT_C 0.01f

// async global->LDS, 16B per lane. HW: LDS dest = wave-uniform base + lane*16,
// global src per-lane (guide §5). Our pattern is exactly linear per-wave.
__device__ __forceinline__ void gload_lds16(const float* g, float* l) {
    __builtin_amdgcn_global_load_lds(
        (const __attribute__((address_space(1))) void*)g,
        (__attribute__((address_space(3))) void*)l,
        16, 0, 0);
}

// B = 262144 (grid divides exactly; no tail guard so waves stay uniform)
__global__ __launch_bounds__(256, 2) void eskf_kernel(
    const float* __restrict__ x,      // (14, B)
    const float* __restrict__ state,  // (B, 7)
    const float* __restrict__ cov,    // (B, 36)
    const float* __restrict__ Qm,     // (B, 36)
    const float* __restrict__ Rm,     // (B, 49)
    float* __restrict__ out,          // (B, 7)
    int B)
{
    __shared__ float ldsR[256 * 49];   // 50176 B
    __shared__ float ldsS[256 * 7];    //  7168 B  (state, then reused for out)

    const int tid  = threadIdx.x;
    const int lane = tid & 63;
    const int wave = tid >> 6;
    const int b    = blockIdx.x * 256 + tid;
    const int eb   = blockIdx.x * 256 + wave * 64;   // this wave's element base

    // ---- issue async staging: state (112 f4/wave), then R (784 f4/wave) ----
    {
        const float* gs = state + (size_t)eb * 7;    // 64*7 floats, 16B-aligned
        float*       ls = ldsS + wave * (64 * 7);
        gload_lds16(gs + 4 * lane, ls + 4 * lane);
        if (lane < 48) gload_lds16(gs + 4 * (64 + lane), ls + 4 * (64 + lane));

        const float* gr = Rm + (size_t)eb * 49;      // 64*49 floats, 16B-aligned
        float*       lr = ldsR + wave * (64 * 49);
#pragma unroll
        for (int k = 0; k < 12; ++k)
            gload_lds16(gr + 4 * (k * 64 + lane), lr + 4 * (k * 64 + lane));
        if (lane < 16)
            gload_lds16(gr + 4 * (768 + lane), lr + 4 * (768 + lane));
    }

    // ---- direct vector loads: cov, Q (dense float4, 16B-aligned) ----
    float4 cv[9], qv[9];
    {
        const float4* c4 = (const float4*)(cov + (size_t)b * 36);
        const float4* q4 = (const float4*)(Qm  + (size_t)b * 36);
#pragma unroll
        for (int i = 0; i < 9; ++i) cv[i] = c4[i];
#pragma unroll
        for (int i = 0; i < 9; ++i) qv[i] = q4[i];
    }

    // x rows: lane-contiguous, perfectly coalesced
    float meas[7], tw[6];
#pragma unroll
    for (int i = 0; i < 7; ++i) meas[i] = x[i * B + b];
#pragma unroll
    for (int i = 0; i < 6; ++i) tw[i] = x[(8 + i) * B + b];

    // P = cov + Q
    float P[36];
#pragma unroll
    for (int i = 0; i < 9; ++i) {
        P[4 * i + 0] = cv[i].x + qv[i].x;
        P[4 * i + 1] = cv[i].y + qv[i].y;
        P[4 * i + 2] = cv[i].z + qv[i].z;
        P[4 * i + 3] = cv[i].w + qv[i].w;
    }

    // ---- staging fence: all gload_lds of this wave complete ----
    asm volatile("s_waitcnt vmcnt(0)" ::: "memory");

    // state from LDS: stride 7 (odd) -> conflict-free scalar reads
    float st[7];
    {
        const float* ls = ldsS + wave * (64 * 7) + lane * 7;
#pragma unroll
        for (int i = 0; i < 7; ++i) st[i] = ls[i];
    }

    // S = R from LDS: stride 49 (gcd(49,32)=1) -> conflict-free scalar reads
    float S[7][7];
    {
        const float* lr = ldsR + wave * (64 * 49) + lane * 49;
#pragma unroll
        for (int i = 0; i < 7; ++i)
#pragma unroll
            for (int j = 0; j < 7; ++j) S[i][j] = lr[i * 7 + j];
    }

    // ---- predict_state = inject(state, DT*twist) ----
    float ps[7];
    {
        float d0 = 0.5f * DT_C * tw[3], d1 = 0.5f * DT_C * tw[4], d2 = 0.5f * DT_C * tw[5];
        ps[0] = st[0] + DT_C * tw[0];
        ps[1] = st[1] + DT_C * tw[1];
        ps[2] = st[2] + DT_C * tw[2];
        float w = st[3], xx = st[4], yy = st[5], zz = st[6];
        float qw = w - xx * d0 - yy * d1 - zz * d2;
        float qx = w * d0 + xx + yy * d2 - zz * d1;
        float qy = w * d1 - xx * d2 + yy + zz * d0;
        float qz = w * d2 + xx * d1 - yy * d0 + zz;
        float inv = rsqrtf(qw * qw + qx * qx + qy * qy + qz * qz);
        ps[3] = qw * inv; ps[4] = qx * inv; ps[5] = qy * inv; ps[6] = qz * inv;
    }

    // ---- Qd from ORIGINAL state quat ----
    float Qd[4][3];
    {
        float w = st[3], xx = st[4], yy = st[5], zz = st[6];
        Qd[0][0] = -0.5f * xx; Qd[0][1] = -0.5f * yy; Qd[0][2] = -0.5f * zz;
        Qd[1][0] =  0.5f * w;  Qd[1][1] = -0.5f * zz; Qd[1][2] =  0.5f * yy;
        Qd[2][0] =  0.5f * zz; Qd[2][1] =  0.5f * w;  Qd[2][2] = -0.5f * xx;
        Qd[3][0] = -0.5f * yy; Qd[3][1] =  0.5f * xx; Qd[3][2] =  0.5f * w;
    }

    // ---- S = H P H^T + R (block structure) ----
#pragma unroll
    for (int i = 0; i < 3; ++i)
#pragma unroll
        for (int j = 0; j < 3; ++j)
            S[i][j] += P[i * 6 + j];

    float T[4][6];
#pragma unroll
    for (int i = 0; i < 4; ++i)
#pragma unroll
        for (int c = 0; c < 6; ++c) {
            float acc = 0.f;
#pragma unroll
            for (int k = 0; k < 3; ++k) acc += Qd[i][k] * P[(3 + k) * 6 + c];
            T[i][c] = acc;
        }

#pragma unroll
    for (int i = 0; i < 4; ++i)
#pragma unroll
        for (int j = 0; j < 3; ++j) S[3 + i][j] += T[i][j];

#pragma unroll
    for (int i = 0; i < 3; ++i)
#pragma unroll
        for (int j = 0; j < 4; ++j) {
            float acc = 0.f;
#pragma unroll
            for (int k = 0; k < 3; ++k) acc += P[i * 6 + 3 + k] * Qd[j][k];
            S[i][3 + j] += acc;
        }

#pragma unroll
    for (int i = 0; i < 4; ++i)
#pragma unroll
        for (int j = 0; j < 4; ++j) {
            float acc = 0.f;
#pragma unroll
            for (int l = 0; l < 3; ++l) acc += T[i][3 + l] * Qd[j][l];
            S[3 + i][3 + j] += acc;
        }

    // ---- innovation ----
    float y[7];
#pragma unroll
    for (int i = 0; i < 7; ++i) y[i] = meas[i] - ps[i];

    // ---- solve S y = innovation (no-pivot LU; S SPD) ----
#pragma unroll
    for (int k = 0; k < 7; ++k) {
        float inv = 1.0f / S[k][k];
#pragma unroll
        for (int i = k + 1; i < 7; ++i) {
            float f = S[i][k] * inv;
#pragma unroll
            for (int j = k + 1; j < 7; ++j) S[i][j] -= f * S[k][j];
            y[i] -= f * y[k];
        }
    }
#pragma unroll
    for (int k = 6; k >= 0; --k) {
        float acc = y[k];
#pragma unroll
        for (int j = k + 1; j < 7; ++j) acc -= S[k][j] * y[j];
        y[k] = acc / S[k][k];
    }

    // ---- error_state = P @ (H^T y) ----
    float z6[6];
    z6[0] = y[0]; z6[1] = y[1]; z6[2] = y[2];
#pragma unroll
    for (int c = 0; c < 3; ++c) {
        float acc = 0.f;
#pragma unroll
        for (int i = 0; i < 4; ++i) acc += Qd[i][c] * y[3 + i];
        z6[3 + c] = acc;
    }
    float es[6];
#pragma unroll
    for (int i = 0; i < 6; ++i) {
        float acc = 0.f;
#pragma unroll
        for (int j = 0; j < 6; ++j) acc += P[i * 6 + j] * z6[j];
        es[i] = acc;
    }

    // ---- new_state = inject(predict_state, error_state) ----
    float o0 = ps[0] + es[0];
    float o1 = ps[1] + es[1];
    float o2 = ps[2] + es[2];
    float d0 = 0.5f * es[3], d1 = 0.5f * es[4], d2 = 0.5f * es[5];
    float w = ps[3], xx = ps[4], yy = ps[5], zz = ps[6];
    float qw = w - xx * d0 - yy * d1 - zz * d2;
    float qx = w * d0 + xx + yy * d2 - zz * d1;
    float qy = w * d1 - xx * d2 + yy + zz * d0;
    float qz = w * d2 + xx * d1 - yy * d0 + zz;
    float inv = rsqrtf(qw * qw + qx * qx + qy * qy + qz * qz);

    // ---- out via LDS: scalar stride-7 writes -> coalesced float4 stores ----
    {
        float* ol = ldsS + wave * (64 * 7) + lane * 7;   // reuse state buffer
        ol[0] = o0; ol[1] = o1; ol[2] = o2;
        ol[3] = qw * inv; ol[4] = qx * inv; ol[5] = qy * inv; ol[6] = qz * inv;
        asm volatile("s_waitcnt lgkmcnt(0)" ::: "memory");

        float4*       og = (float4*)(out + (size_t)eb * 7);
        const float4* lf = (const float4*)(ldsS + wave * (64 * 7));
        og[lane] = lf[lane];
        if (lane < 48) og[64 + lane] = lf[64 + lane];
    }
}

extern "C" void kernel_launch(void* const* d_in, const int* in_sizes, int n_in,
                              void* d_out, int out_size, void* d_ws, size_t ws_size,
                              hipStream_t stream) {
    const float* x     = (const float*)d_in[0];
    const float* state = (const float*)d_in[1];
    const float* cov   = (const float*)d_in[2];
    const float* Qm    = (const float*)d_in[3];
    const float* Rm    = (const float*)d_in[4];
    float* out = (float*)d_out;
    int B = in_sizes[1] / 7;                 // 262144, divisible by 256
    int grid = B / 256;
    eskf_kernel<<<grid, 256, 0, stream>>>(x, state, cov, Qm, Rm, out, B);
}

// Round 3
// 167.675 us; speedup vs baseline: 1.0775x; 1.0053x over previous
//
#include <hip/hip_runtime.h>

#define DT_C 0.01f

// async global->LDS, 16B per lane. Dest = wave-uniform base + lane*16 (linear);
// global source address is per-lane. Zero VGPRs consumed by the load data.
__device__ __forceinline__ void gload_lds16(const float* g, float* l) {
    __builtin_amdgcn_global_load_lds(
        (const __attribute__((address_space(1))) void*)g,
        (__attribute__((address_space(3))) void*)l,
        16, 0, 0);
}

// One wave per block; each block handles 64 elements. All per-element arrays
// staged via global_load_lds (async, batched, ONE vmcnt wait, no barriers).
// LDS/block = 32768 B -> 5 blocks/CU; ~160KB staging in flight per CU.
__global__ __launch_bounds__(64, 2) void eskf_kernel(
    const float* __restrict__ x,      // (14, B)
    const float* __restrict__ state,  // (B, 7)
    const float* __restrict__ cov,    // (B, 36)
    const float* __restrict__ Qm,     // (B, 36)
    const float* __restrict__ Rm,     // (B, 49)
    float* __restrict__ out,          // (B, 7)
    int B)
{
    __shared__ float ldsC[64 * 36];   //  9216 B
    __shared__ float ldsQ[64 * 36];   //  9216 B
    __shared__ float ldsR[64 * 49];   // 12544 B
    __shared__ float ldsS[64 * 7];    //  1792 B (state, reused for out)

    const int lane = threadIdx.x;            // block == 1 wave
    const int eb   = blockIdx.x * 64;        // element base for this wave
    const int b    = eb + lane;

    // ---- issue ALL staging async (33 instrs, no data regs) ----
    {
        const float* gc = cov + (size_t)eb * 36;   // 576 chunks = 9 instrs
#pragma unroll
        for (int k = 0; k < 9; ++k)
            gload_lds16(gc + 4 * (k * 64 + lane), ldsC + 4 * (k * 64 + lane));

        const float* gq = Qm + (size_t)eb * 36;
#pragma unroll
        for (int k = 0; k < 9; ++k)
            gload_lds16(gq + 4 * (k * 64 + lane), ldsQ + 4 * (k * 64 + lane));

        const float* gr = Rm + (size_t)eb * 49;    // 784 chunks = 12 + 16
#pragma unroll
        for (int k = 0; k < 12; ++k)
            gload_lds16(gr + 4 * (k * 64 + lane), ldsR + 4 * (k * 64 + lane));
        if (lane < 16)
            gload_lds16(gr + 4 * (768 + lane), ldsR + 4 * (768 + lane));

        const float* gs = state + (size_t)eb * 7;  // 112 chunks = 1 + 48
        gload_lds16(gs + 4 * lane, ldsS + 4 * lane);
        if (lane < 48)
            gload_lds16(gs + 4 * (64 + lane), ldsS + 4 * (64 + lane));
    }

    // ---- x rows: dense, coalesced, 13 scalar regs ----
    float meas[7], tw[6];
#pragma unroll
    for (int i = 0; i < 7; ++i) meas[i] = x[i * B + b];
#pragma unroll
    for (int i = 0; i < 6; ++i) tw[i] = x[(8 + i) * B + b];

    // ---- single staging fence ----
    asm volatile("s_waitcnt vmcnt(0)" ::: "memory");

    // P = cov + Q : f4 LDS reads, stride 144B (16B-aligned, conflict-free walk)
    float P[36];
    {
        const float4* c4 = (const float4*)(ldsC + lane * 36);
        const float4* q4 = (const float4*)(ldsQ + lane * 36);
#pragma unroll
        for (int i = 0; i < 9; ++i) {
            float4 a = c4[i], bb = q4[i];
            P[4 * i + 0] = a.x + bb.x;
            P[4 * i + 1] = a.y + bb.y;
            P[4 * i + 2] = a.z + bb.z;
            P[4 * i + 3] = a.w + bb.w;
        }
    }

    // state: stride 7 (odd -> 2-way, free)
    float st[7];
    {
        const float* ls = ldsS + lane * 7;
#pragma unroll
        for (int i = 0; i < 7; ++i) st[i] = ls[i];
    }

    // S = R : stride 49 (odd -> 2-way, free)
    float S[7][7];
    {
        const float* lr = ldsR + lane * 49;
#pragma unroll
        for (int i = 0; i < 7; ++i)
#pragma unroll
            for (int j = 0; j < 7; ++j) S[i][j] = lr[i * 7 + j];
    }

    // ---- predict_state = inject(state, DT*twist) ----
    float ps[7];
    {
        float d0 = 0.5f * DT_C * tw[3], d1 = 0.5f * DT_C * tw[4], d2 = 0.5f * DT_C * tw[5];
        ps[0] = st[0] + DT_C * tw[0];
        ps[1] = st[1] + DT_C * tw[1];
        ps[2] = st[2] + DT_C * tw[2];
        float w = st[3], xx = st[4], yy = st[5], zz = st[6];
        float qw = w - xx * d0 - yy * d1 - zz * d2;
        float qx = w * d0 + xx + yy * d2 - zz * d1;
        float qy = w * d1 - xx * d2 + yy + zz * d0;
        float qz = w * d2 + xx * d1 - yy * d0 + zz;
        float inv = rsqrtf(qw * qw + qx * qx + qy * qy + qz * qz);
        ps[3] = qw * inv; ps[4] = qx * inv; ps[5] = qy * inv; ps[6] = qz * inv;
    }

    // ---- Qd from ORIGINAL state quat ----
    float Qd[4][3];
    {
        float w = st[3], xx = st[4], yy = st[5], zz = st[6];
        Qd[0][0] = -0.5f * xx; Qd[0][1] = -0.5f * yy; Qd[0][2] = -0.5f * zz;
        Qd[1][0] =  0.5f * w;  Qd[1][1] = -0.5f * zz; Qd[1][2] =  0.5f * yy;
        Qd[2][0] =  0.5f * zz; Qd[2][1] =  0.5f * w;  Qd[2][2] = -0.5f * xx;
        Qd[3][0] = -0.5f * yy; Qd[3][1] =  0.5f * xx; Qd[3][2] =  0.5f * w;
    }

    // ---- S = H P H^T + R (block structure) ----
#pragma unroll
    for (int i = 0; i < 3; ++i)
#pragma unroll
        for (int j = 0; j < 3; ++j)
            S[i][j] += P[i * 6 + j];

    float T[4][6];
#pragma unroll
    for (int i = 0; i < 4; ++i)
#pragma unroll
        for (int c = 0; c < 6; ++c) {
            float acc = 0.f;
#pragma unroll
            for (int k = 0; k < 3; ++k) acc += Qd[i][k] * P[(3 + k) * 6 + c];
            T[i][c] = acc;
        }

#pragma unroll
    for (int i = 0; i < 4; ++i)
#pragma unroll
        for (int j = 0; j < 3; ++j) S[3 + i][j] += T[i][j];

#pragma unroll
    for (int i = 0; i < 3; ++i)
#pragma unroll
        for (int j = 0; j < 4; ++j) {
            float acc = 0.f;
#pragma unroll
            for (int k = 0; k < 3; ++k) acc += P[i * 6 + 3 + k] * Qd[j][k];
            S[i][3 + j] += acc;
        }

#pragma unroll
    for (int i = 0; i < 4; ++i)
#pragma unroll
        for (int j = 0; j < 4; ++j) {
            float acc = 0.f;
#pragma unroll
            for (int l = 0; l < 3; ++l) acc += T[i][3 + l] * Qd[j][l];
            S[3 + i][3 + j] += acc;
        }

    // ---- innovation ----
    float y[7];
#pragma unroll
    for (int i = 0; i < 7; ++i) y[i] = meas[i] - ps[i];

    // ---- solve S y = innovation (no-pivot LU; S SPD) ----
#pragma unroll
    for (int k = 0; k < 7; ++k) {
        float inv = 1.0f / S[k][k];
#pragma unroll
        for (int i = k + 1; i < 7; ++i) {
            float f = S[i][k] * inv;
#pragma unroll
            for (int j = k + 1; j < 7; ++j) S[i][j] -= f * S[k][j];
            y[i] -= f * y[k];
        }
    }
#pragma unroll
    for (int k = 6; k >= 0; --k) {
        float acc = y[k];
#pragma unroll
        for (int j = k + 1; j < 7; ++j) acc -= S[k][j] * y[j];
        y[k] = acc / S[k][k];
    }

    // ---- error_state = P @ (H^T y) ----
    float z6[6];
    z6[0] = y[0]; z6[1] = y[1]; z6[2] = y[2];
#pragma unroll
    for (int c = 0; c < 3; ++c) {
        float acc = 0.f;
#pragma unroll
        for (int i = 0; i < 4; ++i) acc += Qd[i][c] * y[3 + i];
        z6[3 + c] = acc;
    }
    float es[6];
#pragma unroll
    for (int i = 0; i < 6; ++i) {
        float acc = 0.f;
#pragma unroll
        for (int j = 0; j < 6; ++j) acc += P[i * 6 + j] * z6[j];
        es[i] = acc;
    }

    // ---- new_state = inject(predict_state, error_state) ----
    float o0 = ps[0] + es[0];
    float o1 = ps[1] + es[1];
    float o2 = ps[2] + es[2];
    float d0 = 0.5f * es[3], d1 = 0.5f * es[4], d2 = 0.5f * es[5];
    float w = ps[3], xx = ps[4], yy = ps[5], zz = ps[6];
    float qw = w - xx * d0 - yy * d1 - zz * d2;
    float qx = w * d0 + xx + yy * d2 - zz * d1;
    float qy = w * d1 - xx * d2 + yy + zz * d0;
    float qz = w * d2 + xx * d1 - yy * d0 + zz;
    float inv = rsqrtf(qw * qw + qx * qx + qy * qy + qz * qz);

    // ---- out via LDS (reuse state buf): scalar stride-7 writes -> f4 stores ----
    {
        float* ol = ldsS + lane * 7;
        ol[0] = o0; ol[1] = o1; ol[2] = o2;
        ol[3] = qw * inv; ol[4] = qx * inv; ol[5] = qy * inv; ol[6] = qz * inv;
        asm volatile("s_waitcnt lgkmcnt(0)" ::: "memory");

        float4*       og = (float4*)(out + (size_t)eb * 7);
        const float4* lf = (const float4*)ldsS;
        og[lane] = lf[lane];
        if (lane < 48) og[64 + lane] = lf[64 + lane];
    }
}

extern "C" void kernel_launch(void* const* d_in, const int* in_sizes, int n_in,
                              void* d_out, int out_size, void* d_ws, size_t ws_size,
                              hipStream_t stream) {
    const float* x     = (const float*)d_in[0];
    const float* state = (const float*)d_in[1];
    const float* cov   = (const float*)d_in[2];
    const float* Qm    = (const float*)d_in[3];
    const float* Rm    = (const float*)d_in[4];
    float* out = (float*)d_out;
    int B = in_sizes[1] / 7;                 // 262144, divisible by 64
    int grid = B / 64;
    eskf_kernel<<<grid, 64, 0, stream>>>(x, state, cov, Qm, Rm, out, B);
}